// Round 1
// baseline (527.682 us; speedup 1.0000x reference)
//
#include <hip/hip_runtime.h>

// Problem constants (B=2, L=512, D_NODE=256, D_PAIR=128)
#define BB   2
#define LL   512
#define DN   256
#define DP   128
#define TJ   64            // j-rows per block in K2
#define LDSW 136           // padded LDS row stride in bf16 elems (+8 -> +16B)

using bf16x8 = __attribute__((ext_vector_type(8))) short;   // 8 bf16 = 4 VGPRs
using f32x4  = __attribute__((ext_vector_type(4))) float;   // MFMA accumulator

__device__ inline unsigned short f2bf(float f) {
    unsigned int u = __float_as_uint(f);
    u += 0x7FFFu + ((u >> 16) & 1u);       // round-to-nearest-even
    return (unsigned short)(u >> 16);
}

// -------- K1: x = layernorm(single); a = x@Wa.T+ba (fp32); b = x@Wb.T+bb (bf16)
__global__ __launch_bounds__(256) void pu_ln_ab(
    const float* __restrict__ single, const float* __restrict__ norm_g,
    const float* __restrict__ norm_b, const float* __restrict__ Wa,
    const float* __restrict__ ba, const float* __restrict__ Wb,
    const float* __restrict__ bbias, float* __restrict__ abuf,
    unsigned short* __restrict__ bbuf)
{
    __shared__ __attribute__((aligned(16))) float xs[DN];
    __shared__ float red[8];
    const int row = blockIdx.x;           // 0..B*L-1
    const int tid = threadIdx.x;          // 0..255

    float v = single[row * DN + tid];
    float s1 = v, s2 = v * v;
    #pragma unroll
    for (int m = 32; m; m >>= 1) {        // wave64 butterfly
        s1 += __shfl_xor(s1, m);
        s2 += __shfl_xor(s2, m);
    }
    const int w = tid >> 6;
    if ((tid & 63) == 0) { red[w] = s1; red[4 + w] = s2; }
    __syncthreads();
    s1 = red[0] + red[1] + red[2] + red[3];
    s2 = red[4] + red[5] + red[6] + red[7];
    const float mu  = s1 * (1.0f / DN);
    const float var = s2 * (1.0f / DN) - mu * mu;
    const float rs  = rsqrtf(var + 1e-5f);
    xs[tid] = (v - mu) * rs * norm_g[tid] + norm_b[tid];
    __syncthreads();

    const int half = tid >> 7, p = tid & 127;
    const float4* W4 = (const float4*)((half ? Wb : Wa) + p * DN);
    const float4* x4 = (const float4*)xs;
    float acc = 0.f;
    #pragma unroll 8
    for (int d = 0; d < DN / 4; d++) {
        float4 wv = W4[d], xv = x4[d];
        acc += wv.x * xv.x + wv.y * xv.y + wv.z * xv.z + wv.w * xv.w;
    }
    acc += (half ? bbias[p] : ba[p]);
    if (half == 0) abuf[row * DP + p] = acc;
    else           bbuf[row * DP + p] = f2bf(acc);
}

// -------- K2: upd = (a_i * b_j) @ Wo.T + bo; out = layernorm(pair + upd)
// One block: one (b,i), 64 j-rows. 4 waves; wave w -> j rows [w*16, w*16+16).
__global__ __launch_bounds__(256) void pu_outer_ln(
    const float* __restrict__ pr, const float* __restrict__ Wo,
    const float* __restrict__ bo, const float* __restrict__ png,
    const float* __restrict__ pnb, const float* __restrict__ abuf,
    const unsigned short* __restrict__ bbuf, float* __restrict__ out)
{
    __shared__ __attribute__((aligned(16))) unsigned short sW[DP * LDSW]; // W_i[p][d] bf16
    __shared__ __attribute__((aligned(16))) unsigned short sB[TJ * LDSW]; // b[jl][d] bf16

    const int jt  = blockIdx.x;           // 0..7
    const int i   = blockIdx.y;           // 0..511
    const int bz  = blockIdx.z;           // 0..1
    const int tid = threadIdx.x;
    const int j0  = jt * TJ;

    const int lane = tid & 63;
    const int w    = tid >> 6;
    const int m    = lane & 15;           // col (p) within 16-tile / A row (j)
    const int q    = lane >> 4;           // quad

    // ---- preload pair tile into VGPRs (overlaps with staging + MFMA)
    const size_t obase = (((size_t)bz * LL + i) * LL + (j0 + w * 16)) * DP;
    float pv[4][8];
    #pragma unroll
    for (int r = 0; r < 4; r++) {
        const size_t rowoff = obase + (size_t)(q * 4 + r) * DP + m;
        #pragma unroll
        for (int t = 0; t < 8; t++) pv[r][t] = pr[rowoff + t * 16];
    }

    // ---- epilogue constants for this lane's p = t*16+m
    float bo_r[8], g_r[8], pb_r[8];
    #pragma unroll
    for (int t = 0; t < 8; t++) {
        bo_r[t] = bo[t * 16 + m];
        g_r[t]  = png[t * 16 + m];
        pb_r[t] = pnb[t * 16 + m];
    }

    // ---- stage W_i = bf16(a[i,d] * Wo[p,d]) : 2048 vec8, 8 per thread
    const float* arow = abuf + ((size_t)bz * LL + i) * DP;
    #pragma unroll
    for (int e = 0; e < 8; e++) {
        const int v  = tid + e * 256;     // 0..2047
        const int pw = v >> 4;            // p row
        const int d0 = (v & 15) * 8;
        const float4* w4 = (const float4*)(Wo + pw * DP + d0);
        const float4* a4 = (const float4*)(arow + d0);
        float4 wa = w4[0], wb = w4[1], aa = a4[0], ab = a4[1];
        uint4 pk;
        pk.x = (unsigned)f2bf(wa.x * aa.x) | ((unsigned)f2bf(wa.y * aa.y) << 16);
        pk.y = (unsigned)f2bf(wa.z * aa.z) | ((unsigned)f2bf(wa.w * aa.w) << 16);
        pk.z = (unsigned)f2bf(wb.x * ab.x) | ((unsigned)f2bf(wb.y * ab.y) << 16);
        pk.w = (unsigned)f2bf(wb.z * ab.z) | ((unsigned)f2bf(wb.w * ab.w) << 16);
        *(uint4*)&sW[pw * LDSW + d0] = pk;
    }

    // ---- stage b-vectors (already bf16, contiguous 16 KB): 1024 vec8, 4/thread
    const uint4* bsrc = (const uint4*)(bbuf + ((size_t)bz * LL + j0) * DP);
    #pragma unroll
    for (int e = 0; e < 4; e++) {
        const int v  = tid + e * 256;     // 0..1023
        const int jr = v >> 4;
        const int d0 = (v & 15) * 8;
        *(uint4*)&sB[jr * LDSW + d0] = bsrc[v];
    }
    __syncthreads();

    // ---- MFMA: C[16j x 128p] per wave, K=128 in 4 steps of 32
    f32x4 acc[8];
    #pragma unroll
    for (int t = 0; t < 8; t++) { f32x4 z = {0.f, 0.f, 0.f, 0.f}; acc[t] = z; }

    const unsigned short* Abase = sB + (w * 16 + m) * LDSW + q * 8;
    const unsigned short* Bbase = sW + m * LDSW + q * 8;
    #pragma unroll
    for (int s = 0; s < 4; s++) {
        bf16x8 af = *(const bf16x8*)(Abase + s * 32);
        #pragma unroll
        for (int t = 0; t < 8; t++) {
            bf16x8 bf = *(const bf16x8*)(Bbase + t * 16 * LDSW + s * 32);
            acc[t] = __builtin_amdgcn_mfma_f32_16x16x32_bf16(af, bf, acc[t], 0, 0, 0);
        }
    }

    // ---- epilogue: +pair +bo, row layernorm over p (16-lane reduce), store
    #pragma unroll
    for (int r = 0; r < 4; r++) {
        const size_t rowoff = obase + (size_t)(q * 4 + r) * DP + m;
        float v[8], s1 = 0.f, s2 = 0.f;
        #pragma unroll
        for (int t = 0; t < 8; t++) {
            v[t] = pv[r][t] + acc[t][r] + bo_r[t];
            s1 += v[t];
            s2 += v[t] * v[t];
        }
        s1 += __shfl_xor(s1, 1); s2 += __shfl_xor(s2, 1);
        s1 += __shfl_xor(s1, 2); s2 += __shfl_xor(s2, 2);
        s1 += __shfl_xor(s1, 4); s2 += __shfl_xor(s2, 4);
        s1 += __shfl_xor(s1, 8); s2 += __shfl_xor(s2, 8);
        const float mu  = s1 * (1.0f / DP);
        const float var = s2 * (1.0f / DP) - mu * mu;
        const float rs  = rsqrtf(var + 1e-5f);
        #pragma unroll
        for (int t = 0; t < 8; t++)
            out[rowoff + t * 16] = (v[t] - mu) * rs * g_r[t] + pb_r[t];
    }
}

extern "C" void kernel_launch(void* const* d_in, const int* in_sizes, int n_in,
                              void* d_out, int out_size, void* d_ws, size_t ws_size,
                              hipStream_t stream) {
    const float* single = (const float*)d_in[0];
    const float* pair   = (const float*)d_in[1];
    const float* norm_g = (const float*)d_in[2];
    const float* norm_b = (const float*)d_in[3];
    const float* Wa     = (const float*)d_in[4];
    const float* ba     = (const float*)d_in[5];
    const float* Wb     = (const float*)d_in[6];
    const float* bb     = (const float*)d_in[7];
    const float* Wo     = (const float*)d_in[8];
    const float* bo     = (const float*)d_in[9];
    const float* png    = (const float*)d_in[10];
    const float* pnb    = (const float*)d_in[11];
    float* out = (float*)d_out;

    float* abuf = (float*)d_ws;                                        // 512 KB fp32
    unsigned short* bbuf =
        (unsigned short*)((char*)d_ws + (size_t)BB * LL * DP * sizeof(float)); // 256 KB bf16

    pu_ln_ab<<<dim3(BB * LL), dim3(256), 0, stream>>>(
        single, norm_g, norm_b, Wa, ba, Wb, bb, abuf, bbuf);

    pu_outer_ln<<<dim3(LL / TJ, LL, BB), dim3(256), 0, stream>>>(
        pair, Wo, bo, png, pnb, abuf, bbuf, out);
}